// Round 4
// baseline (743.443 us; speedup 1.0000x reference)
//
#include <hip/hip_runtime.h>

// LoRA linear, RE-FUSED single kernel: each block owns 16 rows end-to-end.
// t = x @ A^T (16x16 per block, lives in LDS only), out = t @ B^T (16x4096).
// No cross-block dependency -> no grid sync, no t round-trip, one launch.
//
// R5 rationale: round-3 null result => both phases are at their stream floors;
// the remaining ~40 us over the 84 us (536 MB @ 6.4 TB/s) floor is structural:
// 2 launches + the global phase-1->phase-2 drain boundary + t_buf traffic.
// Fusion keeps round-3's phase-A pipeline (LDS-staged A, counted-wait barrier)
// and rounds 1-3's phase-B store path (B rows in regs, PLAIN f4 stores that
// assemble full lines in L2 -- round-0's nt stores caused write amplification).

typedef float f4 __attribute__((ext_vector_type(4)));

#define M_TOTAL 16384
#define K_DIM 4096
#define N_DIM 4096
#define R_DIM 16

#define KC 256
#define NCHUNK (K_DIM / KC)   // 16

// LDS-visibility barrier WITHOUT the vmcnt(0) drain of __syncthreads().
#define LDS_BARRIER() asm volatile("s_waitcnt lgkmcnt(0)\n\ts_barrier" ::: "memory")

__global__ __launch_bounds__(256, 2)
void lora_fused(const float* __restrict__ x, const float* __restrict__ A,
                const float* __restrict__ Bm, float* __restrict__ out)
{
    __shared__ float A_lds[2][R_DIM][KC];    // 32 KiB, double-buffered A chunks
    __shared__ float t_lds[16][R_DIM];       // 1 KiB, this block's t rows

    const int tid  = threadIdx.x;
    const int wave = tid >> 6;
    const int lane = tid & 63;
    const int block_row0 = blockIdx.x * 16;
    const int wave_row0  = block_row0 + wave * 4;

    // ---------------- Phase A: t = x @ A^T (pipelined, from round 3) ----------------
    float acc[4][R_DIM];
    #pragma unroll
    for (int w = 0; w < 4; ++w)
        #pragma unroll
        for (int r = 0; r < R_DIM; ++r) acc[w][r] = 0.0f;

    const f4* xr0 = reinterpret_cast<const f4*>(x + (size_t)(wave_row0 + 0) * K_DIM);
    const f4* xr1 = reinterpret_cast<const f4*>(x + (size_t)(wave_row0 + 1) * K_DIM);
    const f4* xr2 = reinterpret_cast<const f4*>(x + (size_t)(wave_row0 + 2) * K_DIM);
    const f4* xr3 = reinterpret_cast<const f4*>(x + (size_t)(wave_row0 + 3) * K_DIM);

    // Prologue: A chunk-0 loads (oldest), x chunk-0 loads, stage A, barrier.
    f4 sreg[4];
    #pragma unroll
    for (int p = 0; p < 4; ++p)
        sreg[p] = *reinterpret_cast<const f4*>(A + (size_t)(p * 4 + wave) * K_DIM + lane * 4);

    f4 xv0 = __builtin_nontemporal_load(&xr0[lane]);
    f4 xv1 = __builtin_nontemporal_load(&xr1[lane]);
    f4 xv2 = __builtin_nontemporal_load(&xr2[lane]);
    f4 xv3 = __builtin_nontemporal_load(&xr3[lane]);

    #pragma unroll
    for (int p = 0; p < 4; ++p)   // ds_write waits vmcnt(4): A landed, x in flight
        *reinterpret_cast<f4*>(&A_lds[0][p * 4 + wave][lane * 4]) = sreg[p];
    LDS_BARRIER();

    #pragma unroll 1
    for (int c = 0; c < NCHUNK; ++c) {
        const int cur = c & 1;
        const bool more = (c + 1 < NCHUNK);
        f4 xn0, xn1, xn2, xn3;
        if (more) {
            #pragma unroll
            for (int p = 0; p < 4; ++p)
                sreg[p] = *reinterpret_cast<const f4*>(
                    A + (size_t)(p * 4 + wave) * K_DIM + (c + 1) * KC + lane * 4);
            const int nidx = (c + 1) * 64 + lane;
            xn0 = __builtin_nontemporal_load(&xr0[nidx]);
            xn1 = __builtin_nontemporal_load(&xr1[nidx]);
            xn2 = __builtin_nontemporal_load(&xr2[nidx]);
            xn3 = __builtin_nontemporal_load(&xr3[nidx]);
        }

        #pragma unroll
        for (int r = 0; r < R_DIM; ++r) {
            f4 av = *reinterpret_cast<const f4*>(&A_lds[cur][r][lane * 4]);
            acc[0][r] += xv0[0] * av[0] + xv0[1] * av[1] + xv0[2] * av[2] + xv0[3] * av[3];
            acc[1][r] += xv1[0] * av[0] + xv1[1] * av[1] + xv1[2] * av[2] + xv1[3] * av[3];
            acc[2][r] += xv2[0] * av[0] + xv2[1] * av[1] + xv2[2] * av[2] + xv2[3] * av[3];
            acc[3][r] += xv3[0] * av[0] + xv3[1] * av[1] + xv3[2] * av[2] + xv3[3] * av[3];
        }

        if (more) {
            #pragma unroll
            for (int p = 0; p < 4; ++p)
                *reinterpret_cast<f4*>(&A_lds[cur ^ 1][p * 4 + wave][lane * 4]) = sreg[p];
            xv0 = xn0; xv1 = xn1; xv2 = xn2; xv3 = xn3;
        }
        LDS_BARRIER();
    }

    // Wave-wide butterfly reduction of all 64 partials -> t_lds.
    #pragma unroll
    for (int w = 0; w < 4; ++w) {
        #pragma unroll
        for (int r = 0; r < R_DIM; ++r) {
            float v = acc[w][r];
            v += __shfl_xor(v, 32, 64);
            v += __shfl_xor(v, 16, 64);
            v += __shfl_xor(v,  8, 64);
            v += __shfl_xor(v,  4, 64);
            v += __shfl_xor(v,  2, 64);
            v += __shfl_xor(v,  1, 64);
            acc[w][r] = v;
        }
    }
    if (lane == 0) {
        #pragma unroll
        for (int w = 0; w < 4; ++w)
            #pragma unroll
            for (int r = 0; r < R_DIM; ++r)
                t_lds[wave * 4 + w][r] = acc[w][r];
    }
    __syncthreads();   // full barrier: t_lds visible to all waves

    // ---------------- Phase B: out = t @ B^T (store path from rounds 1-3) ----------
    // Thread owns 4 consecutive output cols; 256 threads cover 1024 cols; 4 tiles.
    #pragma unroll 1
    for (int ot = 0; ot < N_DIM / 1024; ++ot) {
        const int o0 = ot * 1024 + tid * 4;

        float br[4][R_DIM];              // B rows for my 4 cols (L2-hot)
        #pragma unroll
        for (int oo = 0; oo < 4; ++oo) {
            const f4* bp = reinterpret_cast<const f4*>(Bm + (size_t)(o0 + oo) * R_DIM);
            #pragma unroll
            for (int rc = 0; rc < 4; ++rc) {
                f4 b4 = bp[rc];
                br[oo][rc * 4 + 0] = b4[0];
                br[oo][rc * 4 + 1] = b4[1];
                br[oo][rc * 4 + 2] = b4[2];
                br[oo][rc * 4 + 3] = b4[3];
            }
        }

        #pragma unroll
        for (int m = 0; m < 16; ++m) {
            float tv[R_DIM];
            const f4* tp = reinterpret_cast<const f4*>(&t_lds[m][0]);
            #pragma unroll
            for (int rc = 0; rc < 4; ++rc) {
                f4 t4 = tp[rc];          // same addr across wave: LDS broadcast
                tv[rc * 4 + 0] = t4[0];
                tv[rc * 4 + 1] = t4[1];
                tv[rc * 4 + 2] = t4[2];
                tv[rc * 4 + 3] = t4[3];
            }
            f4 oa = {0.0f, 0.0f, 0.0f, 0.0f};
            #pragma unroll
            for (int r = 0; r < R_DIM; ++r) {
                oa[0] += tv[r] * br[0][r];
                oa[1] += tv[r] * br[1][r];
                oa[2] += tv[r] * br[2][r];
                oa[3] += tv[r] * br[3][r];
            }
            // PLAIN store: assemble full 128B lines in L2, write back once.
            *reinterpret_cast<f4*>(out + (size_t)(block_row0 + m) * N_DIM + o0) = oa;
        }
    }
}

extern "C" void kernel_launch(void* const* d_in, const int* in_sizes, int n_in,
                              void* d_out, int out_size, void* d_ws, size_t ws_size,
                              hipStream_t stream) {
    const float* x  = (const float*)d_in[0];   // [4,4096,4096]
    const float* A  = (const float*)d_in[1];   // [16,4096]
    const float* Bm = (const float*)d_in[2];   // [4096,16]
    float* out = (float*)d_out;                // [4,4096,4096]

    lora_fused<<<dim3(M_TOTAL / 16), dim3(256), 0, stream>>>(x, A, Bm, out);
}